// Round 8
// baseline (29534.210 us; speedup 1.0000x reference)
//
#include <hip/hip_runtime.h>
#include <hip/hip_bf16.h>

typedef float f32x4 __attribute__((ext_vector_type(4)));
typedef __bf16 bf16x8 __attribute__((ext_vector_type(8)));
typedef short s16x8 __attribute__((ext_vector_type(8)));
typedef unsigned short u16;
typedef unsigned long long u64;
typedef unsigned char u8;

constexpr int Bb = 256, Tt = 128, Ff = 256, Hh = 512;
constexpr int TF = Tt * Ff;                       // 32768
constexpr long OFF_RECON = (long)Bb * Tt * Ff;    // 8388608
constexpr long OFF_H     = 2L * Bb * Tt * Ff;     // 16777216
constexpr long OFF_LOSS  = OFF_H + (long)Bb * Hh; // 16908288

__device__ inline float sigf(float v){ return 1.f / (1.f + expf(-v)); }
__device__ inline u16 f2b(float f){
  unsigned u = __float_as_uint(f);
  u += 0x7fffu + ((u >> 16) & 1u);   // RNE
  return (u16)(u >> 16);
}
__device__ inline float b2f(u16 b){ return __uint_as_float(((unsigned)b) << 16); }

// ---- fp8 e4m3 (OCP) conversion ----
__device__ inline unsigned f2e4_sw(float f){
  unsigned u = __float_as_uint(f);
  unsigned s = (u >> 24) & 0x80u;
  int e = (int)((u >> 23) & 0xff) - 127;
  unsigned m = u & 0x7fffffu;
  if (((u >> 23) & 0xff) == 0xff) return s | 0x7e;
  if (e > 8 || (e == 8 && m > 0x600000)) return s | 0x7e;
  if (e < -10) return s;
  if (e >= -6) {
    unsigned keep = m >> 20, rest = m & 0xfffffu;
    keep += (rest > 0x80000u) || (rest == 0x80000u && (keep & 1));
    unsigned ee = (unsigned)(e + 7);
    if (keep == 8) { keep = 0; ee += 1; }
    if (ee >= 16) return s | 0x7e;
    return s | (ee << 3) | keep;
  }
  unsigned full = (1u << 23) | m;
  int shift = 20 + (-6 - e);
  unsigned keep = full >> shift;
  unsigned rest = full & ((1u << shift) - 1u);
  unsigned half = 1u << (shift - 1);
  keep += (rest > half) || (rest == half && (keep & 1));
  return s | keep;
}
__device__ inline unsigned f2e4(float f){
#if __has_builtin(__builtin_amdgcn_cvt_pk_fp8_f32)
  return (unsigned)__builtin_amdgcn_cvt_pk_fp8_f32(f, f, 0, false) & 0xffu;
#else
  return f2e4_sw(f);
#endif
}
__device__ inline unsigned pk2e4(float a, float b){
#if __has_builtin(__builtin_amdgcn_cvt_pk_fp8_f32)
  return (unsigned)__builtin_amdgcn_cvt_pk_fp8_f32(a, b, 0, false) & 0xffffu;
#else
  return f2e4_sw(a) | (f2e4_sw(b) << 8);
#endif
}

__device__ inline f32x4 mfma16(bf16x8 a, bf16x8 b, f32x4 c){
  return __builtin_amdgcn_mfma_f32_16x16x32_bf16(a, b, c, 0, 0, 0);
}
__device__ inline f32x4 mfma8(u64 a, u64 b, f32x4 c){
  return __builtin_amdgcn_mfma_f32_16x16x32_fp8_fp8((long)a, (long)b, c, 0, 0, 0);
}
__device__ inline bf16x8 ldb8(const u16* p){ return *reinterpret_cast<const bf16x8*>(p); }
__device__ inline bf16x8 cvt8(const float* p){
  const float4 a = ((const float4*)p)[0], b = ((const float4*)p)[1];
  s16x8 r;
  r[0]=f2b(a.x); r[1]=f2b(a.y); r[2]=f2b(a.z); r[3]=f2b(a.w);
  r[4]=f2b(b.x); r[5]=f2b(b.y); r[6]=f2b(b.z); r[7]=f2b(b.w);
  return __builtin_bit_cast(bf16x8, r);
}

// ---------------- hoisted big GEMMs (gamma_h, beta for all t; [t][b] layout) ----------------
enum { M_GH, M_BETA };

struct P {
  const float *x, *mask, *deltas;
  const float *b_gh, *w_gx, *b_gx, *b_comb;
  const u16 *Wgh, *Wcomb;
  u16 *gammah, *beta;
};

template<int MODE>
__global__ __launch_bounds__(256) void gk(P p)
{
  constexpr int K = (MODE==M_GH) ? 256 : 512;
  const int lane = threadIdx.x & 63;
  const int w = threadIdx.x >> 6;
  const int m0 = blockIdx.y*64 + (w>>1)*32;
  const int n0 = blockIdx.x*64 + (w&1)*32;
  const int fr = lane & 15;
  const int kg = (lane >> 4) << 3;

  f32x4 acc[2][2] = {};
  for (int k = 0; k < K; k += 32) {
    const int kk = k + kg;
    bf16x8 a[2], b[2];
    #pragma unroll
    for (int r = 0; r < 2; ++r) {
      const int mr = m0 + 16*r + fr;
      if constexpr (MODE == M_GH) {
        a[r] = cvt8(p.deltas + (size_t)mr*256 + kk);
      } else {
        if (kk < 256) {
          const float4 d0 = *(const float4*)(p.deltas + (size_t)mr*256 + kk);
          const float4 d1 = *(const float4*)(p.deltas + (size_t)mr*256 + kk + 4);
          const float4 w0 = *(const float4*)(p.w_gx + kk);
          const float4 w1 = *(const float4*)(p.w_gx + kk + 4);
          const float4 g0 = *(const float4*)(p.b_gx + kk);
          const float4 g1 = *(const float4*)(p.b_gx + kk + 4);
          s16x8 v;
          v[0]=f2b(expf(-fmaxf(d0.x*w0.x+g0.x,0.f)));
          v[1]=f2b(expf(-fmaxf(d0.y*w0.y+g0.y,0.f)));
          v[2]=f2b(expf(-fmaxf(d0.z*w0.z+g0.z,0.f)));
          v[3]=f2b(expf(-fmaxf(d0.w*w0.w+g0.w,0.f)));
          v[4]=f2b(expf(-fmaxf(d1.x*w1.x+g1.x,0.f)));
          v[5]=f2b(expf(-fmaxf(d1.y*w1.y+g1.y,0.f)));
          v[6]=f2b(expf(-fmaxf(d1.z*w1.z+g1.z,0.f)));
          v[7]=f2b(expf(-fmaxf(d1.w*w1.w+g1.w,0.f)));
          a[r] = __builtin_bit_cast(bf16x8, v);
        } else {
          a[r] = cvt8(p.mask + (size_t)mr*256 + (kk-256));
        }
      }
    }
    #pragma unroll
    for (int cc = 0; cc < 2; ++cc) {
      const int nr = n0 + 16*cc + fr;
      if constexpr (MODE == M_GH) b[cc] = ldb8(p.Wgh   + (size_t)nr*256 + kk);
      else                        b[cc] = ldb8(p.Wcomb + (size_t)nr*512 + kk);
    }
    #pragma unroll
    for (int r = 0; r < 2; ++r)
      #pragma unroll
      for (int cc = 0; cc < 2; ++cc)
        acc[r][cc] = mfma16(a[r], b[cc], acc[r][cc]);
  }

  #pragma unroll
  for (int r = 0; r < 2; ++r)
    #pragma unroll
    for (int cc = 0; cc < 2; ++cc)
      #pragma unroll
      for (int q = 0; q < 4; ++q) {
        const int m = m0 + 16*r + (lane>>4)*4 + q;   // m = b*128 + t
        const int n = n0 + 16*cc + (lane&15);
        const size_t tb = (size_t)(m & 127)*256 + (m >> 7);   // [t][b]
        if constexpr (MODE == M_GH) {
          float v = expf(-fmaxf(acc[r][cc][q] + p.b_gh[n], 0.f));
          p.gammah[tb*512 + n] = f2b(v);
        } else {
          float v = sigf(acc[r][cc][q] + p.b_comb[n]);
          p.beta[tb*256 + n] = f2b(v);
        }
      }
}

// ---------------- weight conversion / den / final ----------------
constexpr int CV_TOT = 131072+131072+65536+131072; // bf16 ones
__global__ __launch_bounds__(256) void k_conv(
    const float* Wgh, const float* Whist, const float* Wfr, const float* Wcomb,
    u16* ogh, u16* ohist, u16* ofr, u16* ocomb)
{
  int i = blockIdx.x*256 + threadIdx.x;
  if (i >= CV_TOT) return;
  int j = i;
  if (j < 131072) { ogh[j] = f2b(Wgh[j]); return; }       j -= 131072;
  if (j < 131072) { ohist[j] = f2b(Whist[j]); return; }   j -= 131072;
  if (j < 65536)  { ofr[j] = ((j>>8)==(j&255)) ? (u16)0 : f2b(Wfr[j]); return; } j -= 65536;
  ocomb[j] = f2b(Wcomb[j]);
}

__global__ __launch_bounds__(256) void k_conv8(
    const float* Wih, const float* Whh, u8* oih, u8* ohh)
{
  int i = blockIdx.x*256 + threadIdx.x;   // pair index, total 1048576
  if (i < 524288) {
    ((u16*)oih)[i] = (u16)pk2e4(Wih[2*i], Wih[2*i+1]);
  } else {
    int j = i - 524288;
    ((u16*)ohh)[j] = (u16)pk2e4(Whh[2*j], Whh[2*j+1]);
  }
}

__global__ __launch_bounds__(256) void k_den(const float* __restrict__ mask,
                                             float* den, u8* mask8)
{
  const int t = blockIdx.x;
  const int f = threadIdx.x;
  float s = 0.f;
  for (int b = 0; b < Bb; ++b) {
    float mv = mask[(size_t)b*TF + (size_t)t*256 + f];
    s += mv;
    mask8[((size_t)t*256 + b)*256 + f] = (u8)f2e4(mv);
  }
  __shared__ float red[4];
  #pragma unroll
  for (int o = 32; o; o >>= 1) s += __shfl_down(s, o);
  if ((f & 63) == 0) red[f >> 6] = s;
  __syncthreads();
  if (f == 0) den[t] = red[0]+red[1]+red[2]+red[3];
}

__global__ void k_final(const float* num, const float* den, float* out)
{
  if (threadIdx.x < 64) {
    int t = threadIdx.x;
    float s = num[t]/(den[t]+1e-12f) + num[t+64]/(den[t+64]+1e-12f);
    #pragma unroll
    for (int o = 32; o; o >>= 1) s += __shfl_down(s, o);
    if (t == 0) { out[OFF_LOSS] = s; out[OFF_LOSS+1] = 0.f; }
  }
}

// ---------------- recurrence: 16 fully-independent blocks, 16 rows each ----------------
struct PP {
  const float *x, *mask;
  const float *b_hist, *b_fr, *b_ih, *b_hh;
  const u16 *Whist, *Wfr, *gammah, *beta;
  const u8 *Wih8, *Whh8, *mask8;
  float *num, *out;
};

// LDS layout (byte offsets), per block:
//  h_bf[2]  : [16][520] u16  @ 0 / 16640        (bf16 h, double-buffered)
//  h_f8[2]  : [16][528] u8   @ 33280 / 41728    (fp8 h copy)
//  xr_s     : [16][264] u16  @ 50176
//  ximp_s   : [16][272] u8   @ 58624            -> total 62976 B
__global__ __launch_bounds__(512, 1) void k_loop(PP p)
{
  __shared__ char smem[62976];

  const int tid = threadIdx.x, lane = tid & 63, w = tid >> 6;
  const int fr = lane & 15, kg = (lane >> 4) << 3;
  const int m0 = blockIdx.x * 16;
  const int nA0 = w * 32;                 // phase A: wave covers 2 n-tiles

  // zero LDS (h buffers must start at 0)
  for (int i = tid; i < 62976/4; i += 512) ((int*)smem)[i] = 0;
  __syncthreads();

  // hoisted per-lane biases
  float bh[2], bf2[2];
  #pragma unroll
  for (int cc = 0; cc < 2; ++cc) {
    bh[cc]  = p.b_hist[nA0 + cc*16 + fr];
    bf2[cc] = p.b_fr  [nA0 + cc*16 + fr];
  }
  float bsum[4][4];
  #pragma unroll
  for (int g = 0; g < 4; ++g)
    #pragma unroll
    for (int cc = 0; cc < 4; ++cc) {
      const int n = g*512 + w*64 + cc*16 + fr;
      bsum[g][cc] = p.b_ih[n] + p.b_hh[n];
    }

  u16* xr_s   = (u16*)(smem + 50176);
  u8*  ximp_s = (u8*)(smem + 58624);

  float c_reg[16];
  #pragma unroll
  for (int j = 0; j < 16; ++j) c_reg[j] = 0.f;
  int hcur = 0;

  for (int t = 0; t < Tt; ++t) {
    const u16* hbr = (const u16*)(smem + hcur*16640);
    const u8*  h8r = (const u8*) (smem + 33280 + hcur*8448);
    u16* hbw = (u16*)(smem + (hcur^1)*16640);
    u8*  h8w = (u8*) (smem + 33280 + (hcur^1)*8448);

    // ===== XH: x_h = h @ Whist^T (K=512), h from LDS =====
    f32x4 acc[2] = {};
    #pragma unroll
    for (int k = 0; k < 16; ++k) {
      bf16x8 a = *(const bf16x8*)(hbr + fr*520 + k*32 + kg);
      #pragma unroll
      for (int cc = 0; cc < 2; ++cc)
        acc[cc] = mfma16(a, ldb8(p.Whist + (size_t)(nA0 + cc*16 + fr)*512 + k*32 + kg), acc[cc]);
    }
    float xhv[8], mmv[8], xxv[8];
    #pragma unroll
    for (int cc = 0; cc < 2; ++cc)
      #pragma unroll
      for (int q = 0; q < 4; ++q) {
        const int e = cc*4 + q;
        const int row = (lane>>4)*4 + q;
        const int n = nA0 + cc*16 + fr;
        const float v = acc[cc][q] + bh[cc];
        xhv[e] = v;
        const size_t gi = (size_t)(m0+row)*TF + (size_t)t*256 + n;
        mmv[e] = __builtin_nontemporal_load(p.mask + gi);
        xxv[e] = __builtin_nontemporal_load(p.x + gi);
        xr_s[row*264 + n] = f2b(mmv[e]*xxv[e] + (1.f-mmv[e])*v);
      }
    __syncthreads();

    // ===== XU: xu = xr @ Wfr_m^T (K=256) =====
    f32x4 acc2[2] = {};
    #pragma unroll
    for (int k = 0; k < 8; ++k) {
      bf16x8 a = *(const bf16x8*)(xr_s + fr*264 + k*32 + kg);
      #pragma unroll
      for (int cc = 0; cc < 2; ++cc)
        acc2[cc] = mfma16(a, ldb8(p.Wfr + (size_t)(nA0 + cc*16 + fr)*256 + k*32 + kg), acc2[cc]);
    }
    float lnum = 0.f;
    #pragma unroll
    for (int cc = 0; cc < 2; ++cc)
      #pragma unroll
      for (int q = 0; q < 4; ++q) {
        const int e = cc*4 + q;
        const int row = (lane>>4)*4 + q;
        const int n = nA0 + cc*16 + fr;
        const float xu  = acc2[cc][q] + bf2[cc];
        const float bet = b2f(__builtin_nontemporal_load(p.beta + ((size_t)t*256 + m0+row)*256 + n));
        const float xc  = bet*xu + (1.f-bet)*xhv[e];
        const size_t gi = (size_t)(m0+row)*TF + (size_t)t*256 + n;
        const float xi = mmv[e]*xxv[e] + (1.f-mmv[e])*xc;
        ximp_s[row*272 + n] = (u8)f2e4(xi);
        __builtin_nontemporal_store(xc, p.out + OFF_RECON + gi);
        __builtin_nontemporal_store(xi, p.out + gi);
        lnum += fabsf(xc - xxv[e])*mmv[e];
      }
    #pragma unroll
    for (int o = 32; o; o >>= 1) lnum += __shfl_down(lnum, o);
    if (lane == 0) atomicAdd(p.num + t, lnum);
    __syncthreads();

    // ===== gates fp8 (K=1024): wave owns 64 h-cols x 4 gates =====
    f32x4 ag[4][4] = {};
    #pragma unroll
    for (int k = 0; k < 8; ++k) {          // K 0..256: x_imp (LDS)
      const u64 a = *(const u64*)(ximp_s + fr*272 + k*32 + kg);
      #pragma unroll
      for (int g = 0; g < 4; ++g)
        #pragma unroll
        for (int cc = 0; cc < 4; ++cc)
          ag[g][cc] = mfma8(a, *(const u64*)(p.Wih8 + (size_t)(g*512 + w*64 + cc*16 + fr)*512 + k*32 + kg), ag[g][cc]);
    }
    #pragma unroll
    for (int k = 0; k < 8; ++k) {          // K 256..512: mask8 (stream)
      const u64 a = __builtin_nontemporal_load(
          (const u64*)(p.mask8 + ((size_t)t*256 + m0 + fr)*256 + k*32 + kg));
      #pragma unroll
      for (int g = 0; g < 4; ++g)
        #pragma unroll
        for (int cc = 0; cc < 4; ++cc)
          ag[g][cc] = mfma8(a, *(const u64*)(p.Wih8 + (size_t)(g*512 + w*64 + cc*16 + fr)*512 + 256 + k*32 + kg), ag[g][cc]);
    }
    #pragma unroll
    for (int k = 0; k < 16; ++k) {         // K 512..1024: h fp8 (LDS)
      const u64 a = *(const u64*)(h8r + fr*528 + k*32 + kg);
      #pragma unroll
      for (int g = 0; g < 4; ++g)
        #pragma unroll
        for (int cc = 0; cc < 4; ++cc)
          ag[g][cc] = mfma8(a, *(const u64*)(p.Whh8 + (size_t)(g*512 + w*64 + cc*16 + fr)*512 + k*32 + kg), ag[g][cc]);
    }

    // ===== fused LSTM (lane-local; writes h into the other LDS buffer) =====
    #pragma unroll
    for (int cc = 0; cc < 4; ++cc)
      #pragma unroll
      for (int q = 0; q < 4; ++q) {
        const int e = cc*4 + q;
        const int row = (lane>>4)*4 + q;
        const int hcol = w*64 + cc*16 + fr;
        const float pi = ag[0][cc][q] + bsum[0][cc];
        const float pf = ag[1][cc][q] + bsum[1][cc];
        const float pg = ag[2][cc][q] + bsum[2][cc];
        const float po = ag[3][cc][q] + bsum[3][cc];
        const float ig = sigf(pi), fg = sigf(pf);
        const float gg = tanhf(pg), og = sigf(po);
        const float cv = fg*c_reg[e] + ig*gg;
        c_reg[e] = cv;
        const float hv = og*tanhf(cv);
        if (t == Tt-1) {
          __builtin_nontemporal_store(hv, p.out + OFF_H + (size_t)(m0+row)*512 + hcol);
        } else {
          const float gn = b2f(__builtin_nontemporal_load(
              p.gammah + ((size_t)(t+1)*256 + m0 + row)*512 + hcol));
          const float hd = hv*gn;
          hbw[row*520 + hcol] = f2b(hd);
          h8w[row*528 + hcol] = (u8)f2e4(hd);
        }
      }
    __syncthreads();
    hcur ^= 1;
  }
}

extern "C" void kernel_launch(void* const* d_in, const int* in_sizes, int n_in,
                              void* d_out, int out_size, void* d_ws, size_t ws_size,
                              hipStream_t stream)
{
  char* wsb = (char*)d_ws;
  float* num   = (float*)(wsb + 0);              //   512 (memset 4096)
  u8*   mask8 = (u8*)(wsb + 4096);               //  8388608  [t][b][f]
  u16*  beta  = (u16*)(wsb + 8392704);           // 16777216  [t][b][f]
  u16*  gammah= (u16*)(wsb + 25169920);          // 33554432  [t][b][h]
  u16*  Whist = (u16*)(wsb + 58724352);          //   262144
  u16*  Wfr   = (u16*)(wsb + 58986496);          //   131072
  u16*  Wgh   = (u16*)(wsb + 59117568);          //   262144
  u16*  Wcomb = (u16*)(wsb + 59379712);          //   262144
  u8*   Wih8  = (u8*)(wsb + 59641856);           //  1048576
  u8*   Whh8  = (u8*)(wsb + 60690432);           //  1048576
  float* den  = (float*)(wsb + 61739008);        //      512  -> 61739520 total

  // zero num on every (graph-replayed) call
  hipMemsetAsync(d_ws, 0, 4096, stream);

  k_conv<<<dim3((CV_TOT+255)/256), dim3(256), 0, stream>>>(
      (const float*)d_in[3], (const float*)d_in[7], (const float*)d_in[9],
      (const float*)d_in[11], Wgh, Whist, Wfr, Wcomb);
  k_conv8<<<dim3(4096), dim3(256), 0, stream>>>(
      (const float*)d_in[13], (const float*)d_in[15], Wih8, Whh8);
  k_den<<<dim3(128), dim3(256), 0, stream>>>((const float*)d_in[1], den, mask8);

  P p{};
  p.x = (const float*)d_in[0];  p.mask = (const float*)d_in[1];
  p.deltas = (const float*)d_in[2];
  p.b_gh = (const float*)d_in[4];  p.w_gx = (const float*)d_in[5];
  p.b_gx = (const float*)d_in[6];  p.b_comb = (const float*)d_in[12];
  p.Wgh = Wgh; p.Wcomb = Wcomb;
  p.gammah = gammah; p.beta = beta;
  gk<M_GH><<<dim3(8, 512), dim3(256), 0, stream>>>(p);    // gamma_h, all t
  gk<M_BETA><<<dim3(4, 512), dim3(256), 0, stream>>>(p);  // beta, all t

  PP q{};
  q.x = (const float*)d_in[0];  q.mask = (const float*)d_in[1];
  q.b_hist = (const float*)d_in[8];  q.b_fr = (const float*)d_in[10];
  q.b_ih = (const float*)d_in[14];   q.b_hh = (const float*)d_in[16];
  q.Whist = Whist; q.Wfr = Wfr; q.gammah = gammah; q.beta = beta;
  q.Wih8 = Wih8; q.Whh8 = Whh8; q.mask8 = mask8;
  q.num = num; q.out = (float*)d_out;
  k_loop<<<dim3(16), dim3(512), 0, stream>>>(q);

  k_final<<<dim3(1), dim3(64), 0, stream>>>(num, den, (float*)d_out);
}

// Round 9
// 8052.717 us; speedup vs baseline: 3.6676x; 3.6676x over previous
//
#include <hip/hip_runtime.h>
#include <hip/hip_bf16.h>

typedef float f32x4 __attribute__((ext_vector_type(4)));
typedef __bf16 bf16x8 __attribute__((ext_vector_type(8)));
typedef short s16x8 __attribute__((ext_vector_type(8)));
typedef unsigned short u16;
typedef unsigned long long u64;
typedef unsigned char u8;

constexpr int Bb = 256, Tt = 128, Ff = 256, Hh = 512;
constexpr int TF = Tt * Ff;                       // 32768
constexpr long OFF_RECON = (long)Bb * Tt * Ff;    // 8388608
constexpr long OFF_H     = 2L * Bb * Tt * Ff;     // 16777216
constexpr long OFF_LOSS  = OFF_H + (long)Bb * Hh; // 16908288

__device__ inline float sigf(float v){ return 1.f / (1.f + expf(-v)); }
__device__ inline u16 f2b(float f){
  unsigned u = __float_as_uint(f);
  u += 0x7fffu + ((u >> 16) & 1u);   // RNE
  return (u16)(u >> 16);
}
__device__ inline float b2f(u16 b){ return __uint_as_float(((unsigned)b) << 16); }

// ---- fp8 e4m3 (OCP) conversion ----
__device__ inline unsigned f2e4_sw(float f){
  unsigned u = __float_as_uint(f);
  unsigned s = (u >> 24) & 0x80u;
  int e = (int)((u >> 23) & 0xff) - 127;
  unsigned m = u & 0x7fffffu;
  if (((u >> 23) & 0xff) == 0xff) return s | 0x7e;
  if (e > 8 || (e == 8 && m > 0x600000)) return s | 0x7e;
  if (e < -10) return s;
  if (e >= -6) {
    unsigned keep = m >> 20, rest = m & 0xfffffu;
    keep += (rest > 0x80000u) || (rest == 0x80000u && (keep & 1));
    unsigned ee = (unsigned)(e + 7);
    if (keep == 8) { keep = 0; ee += 1; }
    if (ee >= 16) return s | 0x7e;
    return s | (ee << 3) | keep;
  }
  unsigned full = (1u << 23) | m;
  int shift = 20 + (-6 - e);
  unsigned keep = full >> shift;
  unsigned rest = full & ((1u << shift) - 1u);
  unsigned half = 1u << (shift - 1);
  keep += (rest > half) || (rest == half && (keep & 1));
  return s | keep;
}
__device__ inline unsigned f2e4(float f){
#if __has_builtin(__builtin_amdgcn_cvt_pk_fp8_f32)
  return (unsigned)__builtin_amdgcn_cvt_pk_fp8_f32(f, f, 0, false) & 0xffu;
#else
  return f2e4_sw(f);
#endif
}
__device__ inline unsigned pk2e4(float a, float b){
#if __has_builtin(__builtin_amdgcn_cvt_pk_fp8_f32)
  return (unsigned)__builtin_amdgcn_cvt_pk_fp8_f32(a, b, 0, false) & 0xffffu;
#else
  return f2e4_sw(a) | (f2e4_sw(b) << 8);
#endif
}
__device__ inline unsigned pk4e4(float a, float b, float c, float d){
#if __has_builtin(__builtin_amdgcn_cvt_pk_fp8_f32)
  int lo = __builtin_amdgcn_cvt_pk_fp8_f32(a, b, 0, false);
  return (unsigned)__builtin_amdgcn_cvt_pk_fp8_f32(c, d, lo & 0xffff, true);
#else
  return f2e4_sw(a) | (f2e4_sw(b)<<8) | (f2e4_sw(c)<<16) | (f2e4_sw(d)<<24);
#endif
}

__device__ inline f32x4 mfma16(bf16x8 a, bf16x8 b, f32x4 c){
  return __builtin_amdgcn_mfma_f32_16x16x32_bf16(a, b, c, 0, 0, 0);
}
__device__ inline f32x4 mfma8(u64 a, u64 b, f32x4 c){
  return __builtin_amdgcn_mfma_f32_16x16x32_fp8_fp8((long)a, (long)b, c, 0, 0, 0);
}
__device__ inline bf16x8 ldb8(const u16* p){ return *reinterpret_cast<const bf16x8*>(p); }
__device__ inline bf16x8 cvt8(const float* p){
  const float4 a = ((const float4*)p)[0], b = ((const float4*)p)[1];
  s16x8 r;
  r[0]=f2b(a.x); r[1]=f2b(a.y); r[2]=f2b(a.z); r[3]=f2b(a.w);
  r[4]=f2b(b.x); r[5]=f2b(b.y); r[6]=f2b(b.z); r[7]=f2b(b.w);
  return __builtin_bit_cast(bf16x8, r);
}

// ---------------- hoisted big GEMMs (gamma_h, beta for all t; [t][b] layout) ----------------
enum { M_GH, M_BETA };

struct P {
  const float *x, *mask, *deltas;
  const float *b_gh, *w_gx, *b_gx, *b_comb;
  const u16 *Wgh, *Wcomb;
  u16 *gammah, *beta;
};

template<int MODE>
__global__ __launch_bounds__(256) void gk(P p)
{
  constexpr int K = (MODE==M_GH) ? 256 : 512;
  const int lane = threadIdx.x & 63;
  const int w = threadIdx.x >> 6;
  const int m0 = blockIdx.y*64 + (w>>1)*32;
  const int n0 = blockIdx.x*64 + (w&1)*32;
  const int fr = lane & 15;
  const int kg = (lane >> 4) << 3;

  f32x4 acc[2][2] = {};
  for (int k = 0; k < K; k += 32) {
    const int kk = k + kg;
    bf16x8 a[2], b[2];
    #pragma unroll
    for (int r = 0; r < 2; ++r) {
      const int mr = m0 + 16*r + fr;
      if constexpr (MODE == M_GH) {
        a[r] = cvt8(p.deltas + (size_t)mr*256 + kk);
      } else {
        if (kk < 256) {
          const float4 d0 = *(const float4*)(p.deltas + (size_t)mr*256 + kk);
          const float4 d1 = *(const float4*)(p.deltas + (size_t)mr*256 + kk + 4);
          const float4 w0 = *(const float4*)(p.w_gx + kk);
          const float4 w1 = *(const float4*)(p.w_gx + kk + 4);
          const float4 g0 = *(const float4*)(p.b_gx + kk);
          const float4 g1 = *(const float4*)(p.b_gx + kk + 4);
          s16x8 v;
          v[0]=f2b(expf(-fmaxf(d0.x*w0.x+g0.x,0.f)));
          v[1]=f2b(expf(-fmaxf(d0.y*w0.y+g0.y,0.f)));
          v[2]=f2b(expf(-fmaxf(d0.z*w0.z+g0.z,0.f)));
          v[3]=f2b(expf(-fmaxf(d0.w*w0.w+g0.w,0.f)));
          v[4]=f2b(expf(-fmaxf(d1.x*w1.x+g1.x,0.f)));
          v[5]=f2b(expf(-fmaxf(d1.y*w1.y+g1.y,0.f)));
          v[6]=f2b(expf(-fmaxf(d1.z*w1.z+g1.z,0.f)));
          v[7]=f2b(expf(-fmaxf(d1.w*w1.w+g1.w,0.f)));
          a[r] = __builtin_bit_cast(bf16x8, v);
        } else {
          a[r] = cvt8(p.mask + (size_t)mr*256 + (kk-256));
        }
      }
    }
    #pragma unroll
    for (int cc = 0; cc < 2; ++cc) {
      const int nr = n0 + 16*cc + fr;
      if constexpr (MODE == M_GH) b[cc] = ldb8(p.Wgh   + (size_t)nr*256 + kk);
      else                        b[cc] = ldb8(p.Wcomb + (size_t)nr*512 + kk);
    }
    #pragma unroll
    for (int r = 0; r < 2; ++r)
      #pragma unroll
      for (int cc = 0; cc < 2; ++cc)
        acc[r][cc] = mfma16(a[r], b[cc], acc[r][cc]);
  }

  #pragma unroll
  for (int r = 0; r < 2; ++r)
    #pragma unroll
    for (int cc = 0; cc < 2; ++cc)
      #pragma unroll
      for (int q = 0; q < 4; ++q) {
        const int m = m0 + 16*r + (lane>>4)*4 + q;   // m = b*128 + t
        const int n = n0 + 16*cc + (lane&15);
        const size_t tb = (size_t)(m & 127)*256 + (m >> 7);   // [t][b]
        if constexpr (MODE == M_GH) {
          float v = expf(-fmaxf(acc[r][cc][q] + p.b_gh[n], 0.f));
          p.gammah[tb*512 + n] = f2b(v);
        } else {
          float v = sigf(acc[r][cc][q] + p.b_comb[n]);
          p.beta[tb*256 + n] = f2b(v);
        }
      }
}

// ---------------- weight conversion / den / final ----------------
constexpr int CV_TOT = 131072+131072+65536+131072; // bf16 ones
__global__ __launch_bounds__(256) void k_conv(
    const float* Wgh, const float* Whist, const float* Wfr, const float* Wcomb,
    u16* ogh, u16* ohist, u16* ofr, u16* ocomb)
{
  int i = blockIdx.x*256 + threadIdx.x;
  if (i >= CV_TOT) return;
  int j = i;
  if (j < 131072) { ogh[j] = f2b(Wgh[j]); return; }       j -= 131072;
  if (j < 131072) { ohist[j] = f2b(Whist[j]); return; }   j -= 131072;
  if (j < 65536)  { ofr[j] = ((j>>8)==(j&255)) ? (u16)0 : f2b(Wfr[j]); return; } j -= 65536;
  ocomb[j] = f2b(Wcomb[j]);
}

__global__ __launch_bounds__(256) void k_conv8(
    const float* Wih, const float* Whh, u8* oih, u8* ohh)
{
  int i = blockIdx.x*256 + threadIdx.x;   // pair index, total 1048576
  if (i < 524288) {
    ((u16*)oih)[i] = (u16)pk2e4(Wih[2*i], Wih[2*i+1]);
  } else {
    int j = i - 524288;
    ((u16*)ohh)[j] = (u16)pk2e4(Whh[2*j], Whh[2*j+1]);
  }
}

__global__ __launch_bounds__(256) void k_den(const float* __restrict__ mask,
                                             float* den, u8* mask8)
{
  const int t = blockIdx.x;
  const int f = threadIdx.x;
  float s = 0.f;
  for (int b = 0; b < Bb; ++b) {
    float mv = mask[(size_t)b*TF + (size_t)t*256 + f];
    s += mv;
    mask8[((size_t)t*256 + b)*256 + f] = (u8)f2e4(mv);
  }
  __shared__ float red[4];
  #pragma unroll
  for (int o = 32; o; o >>= 1) s += __shfl_down(s, o);
  if ((f & 63) == 0) red[f >> 6] = s;
  __syncthreads();
  if (f == 0) den[t] = red[0]+red[1]+red[2]+red[3];
}

__global__ void k_final(const float* num, const float* den, float* out)
{
  if (threadIdx.x < 64) {
    int t = threadIdx.x;
    float s = num[t]/(den[t]+1e-12f) + num[t+64]/(den[t+64]+1e-12f);
    #pragma unroll
    for (int o = 32; o; o >>= 1) s += __shfl_down(s, o);
    if (t == 0) { out[OFF_LOSS] = s; out[OFF_LOSS+1] = 0.f; }
  }
}

// ---------------- per-step kernel A: XH -> xr(LDS) -> XU -> outputs/ximp8 ----------------
struct PA {
  const float *x, *mask, *b_hist, *b_fr;
  const u16 *Whist, *Wfr, *beta, *hdecB;  // hdecB: [256][512] bf16
  u8 *ximp8;                               // [256][256] fp8
  float *num, *out;
};

__global__ __launch_bounds__(512) void k_gA(PA p, int t)
{
  __shared__ u16 xr_s[16*264];
  const int tid = threadIdx.x, lane = tid & 63, w = tid >> 6;
  const int fr = lane & 15, kg = (lane >> 4) << 3;
  const int m0 = blockIdx.x * 16;
  const int nA0 = w * 32;               // 8 waves cover 256 cols

  // XH: x_h = hdec @ Whist^T (K=512)
  f32x4 acc[2] = {};
  #pragma unroll
  for (int k = 0; k < 16; ++k) {
    bf16x8 a = ldb8(p.hdecB + (size_t)(m0 + fr)*512 + k*32 + kg);
    #pragma unroll
    for (int cc = 0; cc < 2; ++cc)
      acc[cc] = mfma16(a, ldb8(p.Whist + (size_t)(nA0 + cc*16 + fr)*512 + k*32 + kg), acc[cc]);
  }
  float xhv[8], mmv[8], xxv[8];
  #pragma unroll
  for (int cc = 0; cc < 2; ++cc)
    #pragma unroll
    for (int q = 0; q < 4; ++q) {
      const int e = cc*4 + q;
      const int row = (lane>>4)*4 + q;
      const int n = nA0 + cc*16 + fr;
      const float v = acc[cc][q] + p.b_hist[n];
      xhv[e] = v;
      const size_t gi = (size_t)(m0+row)*TF + (size_t)t*256 + n;
      mmv[e] = __builtin_nontemporal_load(p.mask + gi);
      xxv[e] = __builtin_nontemporal_load(p.x + gi);
      xr_s[row*264 + n] = f2b(mmv[e]*xxv[e] + (1.f-mmv[e])*v);
    }
  __syncthreads();

  // XU: xu = xr @ Wfr_m^T (K=256)
  f32x4 acc2[2] = {};
  #pragma unroll
  for (int k = 0; k < 8; ++k) {
    bf16x8 a = *(const bf16x8*)(xr_s + fr*264 + k*32 + kg);
    #pragma unroll
    for (int cc = 0; cc < 2; ++cc)
      acc2[cc] = mfma16(a, ldb8(p.Wfr + (size_t)(nA0 + cc*16 + fr)*256 + k*32 + kg), acc2[cc]);
  }
  float lnum = 0.f;
  #pragma unroll
  for (int cc = 0; cc < 2; ++cc)
    #pragma unroll
    for (int q = 0; q < 4; ++q) {
      const int e = cc*4 + q;
      const int row = (lane>>4)*4 + q;
      const int n = nA0 + cc*16 + fr;
      const float xu  = acc2[cc][q] + p.b_fr[n];
      const float bet = b2f(__builtin_nontemporal_load(p.beta + ((size_t)t*256 + m0+row)*256 + n));
      const float xc  = bet*xu + (1.f-bet)*xhv[e];
      const size_t gi = (size_t)(m0+row)*TF + (size_t)t*256 + n;
      const float xi = mmv[e]*xxv[e] + (1.f-mmv[e])*xc;
      p.ximp8[(size_t)(m0+row)*256 + n] = (u8)f2e4(xi);
      __builtin_nontemporal_store(xc, p.out + OFF_RECON + gi);
      __builtin_nontemporal_store(xi, p.out + gi);
      lnum += fabsf(xc - xxv[e])*mmv[e];
    }
  #pragma unroll
  for (int o = 32; o; o >>= 1) lnum += __shfl_down(lnum, o);
  if (lane == 0) atomicAdd(p.num + t, lnum);
}

// ---------------- per-step kernel B: fp8 gates (K=1024) + fused LSTM ----------------
struct PB {
  const float *b_ih, *b_hh;
  const u8 *Wih8, *Whh8, *mask8, *ximp8;
  const u16 *gammah;
  u16 *hdecB; u8 *hdec8;
  float *c, *out;
};

// grid 64: rs = bid&7 (row slab of 32; all col-groups of a slab on one XCD),
// cg = bid>>3 (64 h-cols). wave = (gate g, row-half rh).
__global__ __launch_bounds__(512) void k_gB(PB p, int t)
{
  __shared__ float pre_s[4*32*68];      // 34816 B
  const int tid = threadIdx.x, lane = tid & 63, w = tid >> 6;
  const int fr = lane & 15, kg = (lane >> 4) << 3;
  const int rs = blockIdx.x & 7, cg = blockIdx.x >> 3;
  const int m0 = rs*32, hc0 = cg*64;
  const int g = w & 3, rh = w >> 2;

  f32x4 ag[4] = {};
  #pragma unroll
  for (int k = 0; k < 8; ++k) {         // K 0..256: x_imp fp8
    const u64 a = *(const u64*)(p.ximp8 + (size_t)(m0 + rh*16 + fr)*256 + k*32 + kg);
    #pragma unroll
    for (int cc = 0; cc < 4; ++cc)
      ag[cc] = mfma8(a, *(const u64*)(p.Wih8 + (size_t)(g*512 + hc0 + cc*16 + fr)*512 + k*32 + kg), ag[cc]);
  }
  #pragma unroll
  for (int k = 0; k < 8; ++k) {         // K 256..512: mask fp8
    const u64 a = __builtin_nontemporal_load(
        (const u64*)(p.mask8 + ((size_t)t*256 + m0 + rh*16 + fr)*256 + k*32 + kg));
    #pragma unroll
    for (int cc = 0; cc < 4; ++cc)
      ag[cc] = mfma8(a, *(const u64*)(p.Wih8 + (size_t)(g*512 + hc0 + cc*16 + fr)*512 + 256 + k*32 + kg), ag[cc]);
  }
  #pragma unroll
  for (int k = 0; k < 16; ++k) {        // K 512..1024: h_dec fp8
    const u64 a = *(const u64*)(p.hdec8 + (size_t)(m0 + rh*16 + fr)*512 + k*32 + kg);
    #pragma unroll
    for (int cc = 0; cc < 4; ++cc)
      ag[cc] = mfma8(a, *(const u64*)(p.Whh8 + (size_t)(g*512 + hc0 + cc*16 + fr)*512 + k*32 + kg), ag[cc]);
  }
  #pragma unroll
  for (int cc = 0; cc < 4; ++cc)
    #pragma unroll
    for (int q = 0; q < 4; ++q) {
      const int row = rh*16 + (lane>>4)*4 + q;
      const int col = cc*16 + fr;
      pre_s[(g*32 + row)*68 + col] = ag[cc][q];
    }
  __syncthreads();

  // fused LSTM: thread owns (lrow, 4 cols) of the block's 32x64 tile
  {
    const int lrow = tid >> 4;
    const int lcb  = (tid & 15) * 4;
    float hvv[4], hd[4];
    #pragma unroll
    for (int j = 0; j < 4; ++j) {
      const int n = hc0 + lcb + j;
      const float pi = pre_s[(0*32 + lrow)*68 + lcb + j] + p.b_ih[       n] + p.b_hh[       n];
      const float pf = pre_s[(1*32 + lrow)*68 + lcb + j] + p.b_ih[ 512 + n] + p.b_hh[ 512 + n];
      const float pg = pre_s[(2*32 + lrow)*68 + lcb + j] + p.b_ih[1024 + n] + p.b_hh[1024 + n];
      const float po = pre_s[(3*32 + lrow)*68 + lcb + j] + p.b_ih[1536 + n] + p.b_hh[1536 + n];
      const float ig = sigf(pi), fg = sigf(pf);
      const float gg = tanhf(pg), og = sigf(po);
      const int idx = (m0+lrow)*512 + n;
      const float cv = fg*p.c[idx] + ig*gg;
      p.c[idx] = cv;
      hvv[j] = og*tanhf(cv);
    }
    const int idx0 = (m0+lrow)*512 + hc0 + lcb;
    if (t == Tt-1) {
      #pragma unroll
      for (int j = 0; j < 4; ++j)
        __builtin_nontemporal_store(hvv[j], p.out + OFF_H + idx0 + j);
    } else {
      #pragma unroll
      for (int j = 0; j < 4; ++j) {
        const float gn = b2f(__builtin_nontemporal_load(
            p.gammah + ((size_t)(t+1)*256 + m0 + lrow)*512 + hc0 + lcb + j));
        hd[j] = hvv[j]*gn;
      }
      union { u64 q; u16 h[4]; } pb2;
      pb2.h[0]=f2b(hd[0]); pb2.h[1]=f2b(hd[1]); pb2.h[2]=f2b(hd[2]); pb2.h[3]=f2b(hd[3]);
      *(u64*)(p.hdecB + idx0) = pb2.q;
      *(unsigned*)(p.hdec8 + idx0) = pk4e4(hd[0], hd[1], hd[2], hd[3]);
    }
  }
}

extern "C" void kernel_launch(void* const* d_in, const int* in_sizes, int n_in,
                              void* d_out, int out_size, void* d_ws, size_t ws_size,
                              hipStream_t stream)
{
  char* wsb = (char*)d_ws;
  float* num   = (float*)(wsb + 0);              //      512
  float* c     = (float*)(wsb + 512);            //   524288
  u16*  hdecB  = (u16*)(wsb + 524800);           //   262144
  u8*   hdec8  = (u8*)(wsb + 786944);            //   131072  (memset through 918016)
  float* den   = (float*)(wsb + 918016);         //      512
  u8*   ximp8  = (u8*)(wsb + 918528);            //    65536
  u8*   mask8  = (u8*)(wsb + 984064);            //  8388608  [t][b][f]
  u16*  beta   = (u16*)(wsb + 9372672);          // 16777216  [t][b][f]
  u16*  gammah = (u16*)(wsb + 26149888);         // 33554432  [t][b][h]
  u16*  Whist  = (u16*)(wsb + 59704320);         //   262144
  u16*  Wfr    = (u16*)(wsb + 59966464);         //   131072
  u16*  Wgh    = (u16*)(wsb + 60097536);         //   262144
  u16*  Wcomb  = (u16*)(wsb + 60359680);         //   262144
  u8*   Wih8   = (u8*)(wsb + 60621824);          //  1048576
  u8*   Whh8   = (u8*)(wsb + 61670400);          //  1048576  -> 62718976 total

  // zero num, c, hdecB, hdec8 on every (graph-replayed) call
  hipMemsetAsync(d_ws, 0, 918016, stream);

  k_conv<<<dim3((CV_TOT+255)/256), dim3(256), 0, stream>>>(
      (const float*)d_in[3], (const float*)d_in[7], (const float*)d_in[9],
      (const float*)d_in[11], Wgh, Whist, Wfr, Wcomb);
  k_conv8<<<dim3(4096), dim3(256), 0, stream>>>(
      (const float*)d_in[13], (const float*)d_in[15], Wih8, Whh8);
  k_den<<<dim3(128), dim3(256), 0, stream>>>((const float*)d_in[1], den, mask8);

  P p{};
  p.x = (const float*)d_in[0];  p.mask = (const float*)d_in[1];
  p.deltas = (const float*)d_in[2];
  p.b_gh = (const float*)d_in[4];  p.w_gx = (const float*)d_in[5];
  p.b_gx = (const float*)d_in[6];  p.b_comb = (const float*)d_in[12];
  p.Wgh = Wgh; p.Wcomb = Wcomb;
  p.gammah = gammah; p.beta = beta;
  gk<M_GH><<<dim3(8, 512), dim3(256), 0, stream>>>(p);    // gamma_h, all t
  gk<M_BETA><<<dim3(4, 512), dim3(256), 0, stream>>>(p);  // beta, all t

  PA pa{};
  pa.x = (const float*)d_in[0];  pa.mask = (const float*)d_in[1];
  pa.b_hist = (const float*)d_in[8];  pa.b_fr = (const float*)d_in[10];
  pa.Whist = Whist; pa.Wfr = Wfr; pa.beta = beta; pa.hdecB = hdecB;
  pa.ximp8 = ximp8; pa.num = num; pa.out = (float*)d_out;

  PB pb{};
  pb.b_ih = (const float*)d_in[14]; pb.b_hh = (const float*)d_in[16];
  pb.Wih8 = Wih8; pb.Whh8 = Whh8; pb.mask8 = mask8; pb.ximp8 = ximp8;
  pb.gammah = gammah; pb.hdecB = hdecB; pb.hdec8 = hdec8;
  pb.c = c; pb.out = (float*)d_out;

  for (int t = 0; t < Tt; ++t) {
    k_gA<<<dim3(16), dim3(512), 0, stream>>>(pa, t);
    k_gB<<<dim3(64), dim3(512), 0, stream>>>(pb, t);
  }
  k_final<<<dim3(1), dim3(64), 0, stream>>>(num, den, (float*)d_out);
}